// Round 1
// baseline (13662.354 us; speedup 1.0000x reference)
//
#include <hip/hip_runtime.h>

typedef _Float16 f16x8 __attribute__((ext_vector_type(8)));
typedef _Float16 f16x4 __attribute__((ext_vector_type(4)));
typedef float f32x4 __attribute__((ext_vector_type(4)));

#define T_STEPS 512
#define BATCH   128
#define DIM     512
#define HID     1024
#define KCAT    1536   // DIM + HID
#define G3      3072   // 3*HID
#define NB      128    // blocks in step kernel (all co-resident: <= 256 CUs)

__device__ __forceinline__ f32x4 mfma16(f16x8 a, f16x8 b, f32x4 c) {
  return __builtin_amdgcn_mfma_f32_16x16x32_f16(a, b, c, 0, 0, 0);
}

// ---------------- prep: fp32 -> fp16 conversions, weight repack, init ----------------
__global__ void prep_kernel(const float* __restrict__ x,
                            const float* __restrict__ Wi,
                            const float* __restrict__ Wh,
                            const float* __restrict__ h0,
                            _Float16* __restrict__ x16,
                            _Float16* __restrict__ wcat,   // [3072][1536] = [Wi;Wh]^T
                            _Float16* __restrict__ h16a,
                            float* __restrict__ h32,
                            unsigned* __restrict__ cnt) {
  size_t tid = (size_t)blockIdx.x * blockDim.x + threadIdx.x;
  size_t stride = (size_t)gridDim.x * blockDim.x;

  // x: 33,554,432 elems, vectorized by 4
  const size_t nx4 = (size_t)T_STEPS * BATCH * DIM / 4;
  for (size_t i = tid; i < nx4; i += stride) {
    float4 v = ((const float4*)x)[i];
    f16x4 o;
    o.x = (_Float16)v.x; o.y = (_Float16)v.y; o.z = (_Float16)v.z; o.w = (_Float16)v.w;
    ((f16x4*)x16)[i] = o;
  }

  // wcat[n][k] = (k<512 ? Wi[k][n] : Wh[k-512][n]); n-major so writes coalesce,
  // strided reads are absorbed by L2 (Wi+Wh = 19 MB).
  const size_t nw = (size_t)G3 * KCAT;
  for (size_t i = tid; i < nw; i += stride) {
    size_t n = i / KCAT, k = i % KCAT;
    float v = (k < DIM) ? Wi[k * G3 + n] : Wh[(k - DIM) * G3 + n];
    wcat[i] = (_Float16)v;
  }

  // h init
  for (size_t i = tid; i < (size_t)BATCH * HID; i += stride) {
    float v = h0[i];
    h32[i] = v;
    h16a[i] = (_Float16)v;
  }

  // barrier counters
  for (size_t i = tid; i < T_STEPS; i += stride) cnt[i] = 0u;
}

// ---------------- persistent sequential GRU ----------------
// Grid: 128 blocks x 256 threads. blockIdx = rtg*64 + ct, waves 0..3 -> rt = rtg*4+wave.
// Wave (rt, ct) owns rows [rt*16, rt*16+16) x cols-of-H [ct*16, ct*16+16) for all 3 gates.
__global__ __launch_bounds__(256) void gru_steps(
    const int* __restrict__ resets,
    const float* __restrict__ bi,
    const float* __restrict__ bhn,
    const _Float16* __restrict__ x16,
    const _Float16* __restrict__ wcat,
    _Float16* __restrict__ h16a,
    _Float16* __restrict__ h16b,
    float* __restrict__ h32,
    float* __restrict__ out,
    unsigned* __restrict__ cnt) {
  const int lane = threadIdx.x & 63;
  const int wave = threadIdx.x >> 6;
  const int ct  = blockIdx.x & 63;
  const int rtg = blockIdx.x >> 6;
  const int rt  = rtg * 4 + wave;
  const int arow  = rt * 16 + (lane & 15);       // A-fragment row (batch index)
  const int colH  = ct * 16 + (lane & 15);       // B col within H
  const int kq    = (lane >> 4) * 8;             // k offset within a 32-chunk
  const int crow0 = rt * 16 + (lane >> 4) * 4;   // C/D rows: crow0..crow0+3

  const _Float16* wr = wcat + (size_t)(0 * HID + colH) * KCAT + kq;
  const _Float16* wz = wcat + (size_t)(1 * HID + colH) * KCAT + kq;
  const _Float16* wn = wcat + (size_t)(2 * HID + colH) * KCAT + kq;
  const float bir = bi[colH], biz = bi[HID + colH], bin = bi[2 * HID + colH];
  const float bh = bhn[colH];

  _Float16* hbuf[2] = {h16a, h16b};
  const f16x8 fzero = {};

  for (int t = 0; t < T_STEPS; ++t) {
    const _Float16* hread = hbuf[t & 1];
    _Float16* hwrite = hbuf[(t + 1) & 1];
    const int rst = resets[t * BATCH + arow];
    const _Float16* xa = x16 + ((size_t)t * BATCH + arow) * DIM + kq;
    const _Float16* ha = hread + (size_t)arow * HID + kq;

    f32x4 ar = {0.f, 0.f, 0.f, 0.f};
    f32x4 az = {0.f, 0.f, 0.f, 0.f};
    f32x4 ain = {0.f, 0.f, 0.f, 0.f};
    f32x4 ahn = {0.f, 0.f, 0.f, 0.f};

    // x-path: K = 0..511 (i_r, i_z, i_n)
    #pragma unroll
    for (int c = 0; c < DIM / 32; ++c) {
      f16x8 a = *(const f16x8*)(xa + c * 32);
      ar  = mfma16(a, *(const f16x8*)(wr + c * 32), ar);
      az  = mfma16(a, *(const f16x8*)(wz + c * 32), az);
      ain = mfma16(a, *(const f16x8*)(wn + c * 32), ain);
    }
    // h-path: K = 512..1535 (h_r, h_z, h_n), reset-masked carry
    #pragma unroll
    for (int c = 0; c < HID / 32; ++c) {
      f16x8 a = *(const f16x8*)(ha + c * 32);
      a = rst ? fzero : a;
      ar  = mfma16(a, *(const f16x8*)(wr + DIM + c * 32), ar);
      az  = mfma16(a, *(const f16x8*)(wz + DIM + c * 32), az);
      ahn = mfma16(a, *(const f16x8*)(wn + DIM + c * 32), ahn);
    }

    // elementwise: r,z,n gates + blend; wave-local (C/D tile == owned h tile)
    #pragma unroll
    for (int r = 0; r < 4; ++r) {
      const int row = crow0 + r;
      const float pr = ar[r] + bir;
      const float pz = az[r] + biz;
      const float rg = 1.f / (1.f + __expf(-pr));
      const float zg = 1.f / (1.f + __expf(-pz));
      const float npre = ain[r] + bin + rg * (ahn[r] + bh);
      const float e2 = __expf(2.f * npre);
      const float ng = 1.f - 2.f / (e2 + 1.f);   // tanh, inf-safe
      const int rrst = resets[t * BATCH + row];
      const size_t hidx = (size_t)row * HID + colH;
      const float hprev = rrst ? 0.f : h32[hidx];
      const float hnew = (1.f - zg) * ng + zg * hprev;
      out[(size_t)t * (BATCH * HID) + hidx] = hnew;
      h32[hidx] = hnew;
      hwrite[hidx] = (_Float16)hnew;
    }

    // grid barrier: release h writes, arrive, spin, acquire
    __syncthreads();
    if (threadIdx.x == 0) {
      __threadfence();
      atomicAdd(&cnt[t], 1u);
      while (__hip_atomic_load(&cnt[t], __ATOMIC_RELAXED, __HIP_MEMORY_SCOPE_AGENT) < NB) {
        __builtin_amdgcn_s_sleep(2);
      }
      __threadfence();
    }
    __syncthreads();
  }
}

extern "C" void kernel_launch(void* const* d_in, const int* in_sizes, int n_in,
                              void* d_out, int out_size, void* d_ws, size_t ws_size,
                              hipStream_t stream) {
  const float* x      = (const float*)d_in[0];
  const int*   resets = (const int*)d_in[1];
  const float* h0     = (const float*)d_in[2];
  const float* Wi     = (const float*)d_in[3];
  const float* bi     = (const float*)d_in[4];
  const float* Wh     = (const float*)d_in[5];
  const float* bhn    = (const float*)d_in[6];
  float* out = (float*)d_out;

  char* ws = (char*)d_ws;
  // workspace layout (bytes):
  //   x16:   0          .. 67,108,864   (33.5M fp16)
  //   wcat:  67,108,864 .. 76,546,048   (4.7M fp16)
  //   h16a:  76,546,048 (+262,144)
  //   h16b:  76,808,192 (+262,144)
  //   h32:   77,070,336 (+524,288)
  //   cnt:   77,594,624 (+2,048)
  _Float16* x16  = (_Float16*)(ws);
  _Float16* wcat = (_Float16*)(ws + 67108864);
  _Float16* h16a = (_Float16*)(ws + 76546048);
  _Float16* h16b = (_Float16*)(ws + 76808192);
  float*    h32  = (float*)(ws + 77070336);
  unsigned* cnt  = (unsigned*)(ws + 77594624);

  prep_kernel<<<1024, 256, 0, stream>>>(x, Wi, Wh, h0, x16, wcat, h16a, h32, cnt);
  gru_steps<<<NB, 256, 0, stream>>>(resets, bi, bhn, x16, wcat, h16a, h16b, h32, out, cnt);
}

// Round 3
// 8722.021 us; speedup vs baseline: 1.5664x; 1.5664x over previous
//
#include <hip/hip_runtime.h>

typedef _Float16 f16x8 __attribute__((ext_vector_type(8)));
typedef _Float16 f16x4 __attribute__((ext_vector_type(4)));
typedef float f32x4 __attribute__((ext_vector_type(4)));

#define T_STEPS 512
#define BATCH   128
#define DIM     512
#define HID     1024
#define KCAT    1536   // DIM + HID
#define G3      3072   // 3*HID
#define NBLK    256    // one block per CU
#define GRP     64     // blocks per rtq barrier group

__device__ __forceinline__ f32x4 mfma16(f16x8 a, f16x8 b, f32x4 c) {
  return __builtin_amdgcn_mfma_f32_16x16x32_f16(a, b, c, 0, 0, 0);
}

// ---------------- prep: fp32 -> fp16 conversions, weight repack, init ----------------
__global__ void prep_kernel(const float* __restrict__ x,
                            const float* __restrict__ Wi,
                            const float* __restrict__ Wh,
                            const float* __restrict__ h0,
                            _Float16* __restrict__ x16,
                            _Float16* __restrict__ wcat,   // [3072][1536] = [Wi;Wh]^T
                            _Float16* __restrict__ h16a,
                            unsigned* __restrict__ cnt) {
  size_t tid = (size_t)blockIdx.x * blockDim.x + threadIdx.x;
  size_t stride = (size_t)gridDim.x * blockDim.x;

  const size_t nx4 = (size_t)T_STEPS * BATCH * DIM / 4;
  for (size_t i = tid; i < nx4; i += stride) {
    float4 v = ((const float4*)x)[i];
    f16x4 o;
    o.x = (_Float16)v.x; o.y = (_Float16)v.y; o.z = (_Float16)v.z; o.w = (_Float16)v.w;
    ((f16x4*)x16)[i] = o;
  }

  // wcat[n][k] = (k<512 ? Wi[k][n] : Wh[k-512][n])
  const size_t nw = (size_t)G3 * KCAT;
  for (size_t i = tid; i < nw; i += stride) {
    size_t n = i / KCAT, k = i % KCAT;
    float v = (k < DIM) ? Wi[k * G3 + n] : Wh[(k - DIM) * G3 + n];
    wcat[i] = (_Float16)v;
  }

  for (size_t i = tid; i < (size_t)BATCH * HID; i += stride)
    h16a[i] = (_Float16)h0[i];

  for (size_t i = tid; i < (size_t)4 * T_STEPS; i += stride) cnt[i] = 0u;
}

// ---------------- persistent sequential GRU, weights in VGPRs ----------------
// 256 blocks x 256 threads. block = (rtq = blockIdx&3, ct = blockIdx>>2).
// Block owns output rows [rtq*32, rtq*32+32) x cols-of-H [ct*16, ct*16+16),
// all 3 gates, full K. Waves split K (wave w holds chunks kc = w + 4j, j=0..11,
// 3 gates => 36 B-fragments in registers). K-reduction via LDS (conflict-free).
// Only the 64 blocks sharing rtq synchronize (independent row-group chains).
__global__ __launch_bounds__(256, 1) void gru_steps(
    const int* __restrict__ resets,
    const float* __restrict__ bi,
    const float* __restrict__ bhn,
    const float* __restrict__ h0,
    const _Float16* __restrict__ x16,
    const _Float16* __restrict__ wcat,
    _Float16* __restrict__ h16a,
    _Float16* __restrict__ h16b,
    float* __restrict__ out,
    unsigned* __restrict__ cnt) {
  const int tid  = threadIdx.x;
  const int lane = tid & 63;
  const int wv   = tid >> 6;
  const int rtq  = blockIdx.x & 3;
  const int ct   = blockIdx.x >> 2;
  const int l15  = lane & 15;
  const int kq   = (lane >> 4) * 8;
  const int rowA0 = rtq * 32 + l15;   // A-fragment row for rt=0 (rt=1: +16)

  // ---- load this wave's 36 weight fragments into registers ----
  f16x8 w[3][12];
  #pragma unroll
  for (int g = 0; g < 3; ++g) {
    const _Float16* wp = wcat + (size_t)(g * HID + ct * 16 + l15) * KCAT + kq;
    #pragma unroll
    for (int j = 0; j < 12; ++j)
      w[g][j] = *(const f16x8*)(wp + (wv + 4 * j) * 32);
  }

  // ---- per-thread elementwise constants (2 outputs: rows tid>>4 + {0,16}) ----
  const int colE = tid & 15;
  const int colH = ct * 16 + colE;
  const int lsrc = colE | (wv << 4);      // C-layout source lane (quad == wv)
  const int regE = (tid >> 4) & 3;        // C-layout reg index
  const float bir = bi[colH], biz = bi[HID + colH], bin = bi[2 * HID + colH];
  const float bh  = bhn[colH];
  int rowE[2];
  float hreg[2];
  #pragma unroll
  for (int p = 0; p < 2; ++p) {
    rowE[p] = rtq * 32 + (tid >> 4) + 16 * p;
    hreg[p] = h0[(size_t)rowE[p] * HID + colH];
  }

  __shared__ f32x4 red[4][2][4][64];   // [wave][rt][acc{r,z,nx,nh}][lane], 32 KB

  const f16x8 fzero = {};
  f16x8 ax[2][4];
  int rstA[2], rstE[2];

  // prefetch x-fragments + reset flags for step t
  auto load_x = [&](int t) {
    #pragma unroll
    for (int rt = 0; rt < 2; ++rt) {
      const _Float16* xa = x16 + ((size_t)t * BATCH + rowA0 + rt * 16) * DIM + kq;
      #pragma unroll
      for (int j = 0; j < 4; ++j)
        ax[rt][j] = *(const f16x8*)(xa + (wv + 4 * j) * 32);
      rstA[rt] = resets[t * BATCH + rowA0 + rt * 16];
    }
    #pragma unroll
    for (int p = 0; p < 2; ++p) rstE[p] = resets[t * BATCH + rowE[p]];
  };
  load_x(0);

  for (int t = 0; t < T_STEPS; ++t) {
    const _Float16* hread = (t & 1) ? h16b : h16a;
    _Float16* hwrite      = (t & 1) ? h16a : h16b;

    // h A-fragments (issued first; x-MFMAs below overlap their latency)
    f16x8 ah[2][8];
    #pragma unroll
    for (int rt = 0; rt < 2; ++rt) {
      const _Float16* ha = hread + (size_t)(rowA0 + rt * 16) * HID + kq;
      #pragma unroll
      for (int j = 0; j < 8; ++j)
        ah[rt][j] = *(const f16x8*)(ha + (wv + 4 * j) * 32);
    }

    f32x4 acc[2][4] = {};
    #pragma unroll
    for (int rt = 0; rt < 2; ++rt) {
      #pragma unroll
      for (int j = 0; j < 4; ++j) {        // x-part: kc = wv+4j < 16
        f16x8 a = ax[rt][j];
        acc[rt][0] = mfma16(a, w[0][j], acc[rt][0]);
        acc[rt][1] = mfma16(a, w[1][j], acc[rt][1]);
        acc[rt][2] = mfma16(a, w[2][j], acc[rt][2]);   // i_n partial
      }
      #pragma unroll
      for (int j = 0; j < 8; ++j) {        // h-part (reset-masked carry)
        f16x8 a = rstA[rt] ? fzero : ah[rt][j];
        acc[rt][0] = mfma16(a, w[0][j + 4], acc[rt][0]);
        acc[rt][1] = mfma16(a, w[1][j + 4], acc[rt][1]);
        acc[rt][3] = mfma16(a, w[2][j + 4], acc[rt][3]);  // h_n partial
      }
    }

    // K-reduction across the 4 waves via LDS
    #pragma unroll
    for (int rt = 0; rt < 2; ++rt)
      #pragma unroll
      for (int a = 0; a < 4; ++a)
        red[wv][rt][a][lane] = acc[rt][a];
    __syncthreads();

    // Snapshot THIS step's elementwise reset flags BEFORE the prefetch
    // overwrites rstE with step t+1's flags (round-2 bug: blend used t+1's
    // resets -> absmax 0.96).
    const int rstEcur0 = rstE[0];
    const int rstEcur1 = rstE[1];

    // prefetch next step's x-fragments + resets (hidden under reduce+barrier)
    if (t + 1 < T_STEPS) load_x(t + 1);

    // reduce + gates + blend; each thread owns 2 output elements
    #pragma unroll
    for (int p = 0; p < 2; ++p) {
      float sr = 0.f, sz = 0.f, snx = 0.f, snh = 0.f;
      #pragma unroll
      for (int wi = 0; wi < 4; ++wi) {
        sr  += red[wi][p][0][lsrc][regE];
        sz  += red[wi][p][1][lsrc][regE];
        snx += red[wi][p][2][lsrc][regE];
        snh += red[wi][p][3][lsrc][regE];
      }
      const float rg = 1.f / (1.f + __expf(-(sr + bir)));
      const float zg = 1.f / (1.f + __expf(-(sz + biz)));
      const float npre = snx + bin + rg * (snh + bh);
      const float e2 = __expf(2.f * npre);
      const float ng = 1.f - 2.f / (e2 + 1.f);          // tanh, inf-safe
      const int rstcur = p ? rstEcur1 : rstEcur0;
      const float hprev = rstcur ? 0.f : hreg[p];
      const float hnew = (1.f - zg) * ng + zg * hprev;
      const size_t hidx = (size_t)rowE[p] * HID + colH;
      out[(size_t)t * (BATCH * HID) + hidx] = hnew;
      hwrite[hidx] = (_Float16)hnew;
      hreg[p] = hnew;
    }

    // group barrier: only the 64 blocks sharing rtq (independent row chains).
    // cnt indexed [rtq][t] so groups never share a cache line.
    if (t + 1 < T_STEPS) {
      __syncthreads();
      if (tid == 0) {
        unsigned* c = &cnt[rtq * T_STEPS + t];
        __threadfence();
        atomicAdd(c, 1u);
        while (__hip_atomic_load(c, __ATOMIC_RELAXED, __HIP_MEMORY_SCOPE_AGENT) < GRP)
          __builtin_amdgcn_s_sleep(1);
        __threadfence();
      }
      __syncthreads();
    }
  }
}

extern "C" void kernel_launch(void* const* d_in, const int* in_sizes, int n_in,
                              void* d_out, int out_size, void* d_ws, size_t ws_size,
                              hipStream_t stream) {
  const float* x      = (const float*)d_in[0];
  const int*   resets = (const int*)d_in[1];
  const float* h0     = (const float*)d_in[2];
  const float* Wi     = (const float*)d_in[3];
  const float* bi     = (const float*)d_in[4];
  const float* Wh     = (const float*)d_in[5];
  const float* bhn    = (const float*)d_in[6];
  float* out = (float*)d_out;

  char* ws = (char*)d_ws;
  // workspace layout (bytes):
  //   x16:   0          .. 67,108,864
  //   wcat:  67,108,864 .. 76,546,048
  //   h16a:  76,546,048 (+262,144)
  //   h16b:  76,808,192 (+262,144)
  //   cnt:   77,070,336 (+8,192)
  _Float16* x16  = (_Float16*)(ws);
  _Float16* wcat = (_Float16*)(ws + 67108864);
  _Float16* h16a = (_Float16*)(ws + 76546048);
  _Float16* h16b = (_Float16*)(ws + 76808192);
  unsigned* cnt  = (unsigned*)(ws + 77070336);

  prep_kernel<<<1024, 256, 0, stream>>>(x, Wi, Wh, h0, x16, wcat, h16a, cnt);
  gru_steps<<<NBLK, 256, 0, stream>>>(resets, bi, bhn, h0, x16, wcat,
                                      h16a, h16b, out, cnt);
}